// Round 1
// baseline (1498.144 us; speedup 1.0000x reference)
//
#include <hip/hip_runtime.h>
#include <math.h>

#define BDIM 256

constexpr int B_  = 4;
constexpr int L_  = 500;
constexpr int DM  = 1024;   // d_model
constexpr int DI  = 2048;   // d_inner
constexpr int DXZ = 4096;   // 2*d_inner
constexpr int RNK = 64;     // dt_rank
constexpr int NST = 16;     // d_state
constexpr int NXP = 96;     // dt_rank + 2*d_state
constexpr int M1  = B_ * L_;   // 2000 rows (mamba token count)
constexpr int M2  = 200;       // 4*50 rows (fc1 view)
constexpr int K2  = 10240;     // fc1 K

__device__ __forceinline__ float sigmoidf_(float x) { return 1.0f / (1.0f + __expf(-x)); }

// C[M,N] = A[M,K] * B[N,K]^T, row-major, with optional fused epilogue.
// FUSE: 0 = none, 1 = softplus(x + bias[n]), 2 = tanh(x + bias[n])
template<int FUSE>
__global__ __launch_bounds__(BDIM)
void gemm_nt(const float* __restrict__ A, int lda,
             const float* __restrict__ Bw, int ldb,
             float* __restrict__ C, int ldc,
             int M, int N, int K,
             const float* __restrict__ bias)
{
    __shared__ float As[16][68];
    __shared__ float Bs[16][68];
    const int tid = threadIdx.x;
    const int tx = tid & 15, ty = tid >> 4;
    const int m0 = blockIdx.y * 64;
    const int n0 = blockIdx.x * 64;
    const int lrow = tid >> 2;        // 0..63 (tile row for loads)
    const int lq   = (tid & 3) * 4;   // 0,4,8,12 (k-quad for loads)
    float acc[4][4] = {};
    for (int k0 = 0; k0 < K; k0 += 16) {
        float4 av = make_float4(0.f, 0.f, 0.f, 0.f);
        if (m0 + lrow < M)
            av = *(const float4*)(A + (size_t)(m0 + lrow) * lda + k0 + lq);
        As[lq + 0][lrow] = av.x; As[lq + 1][lrow] = av.y;
        As[lq + 2][lrow] = av.z; As[lq + 3][lrow] = av.w;
        float4 bv = make_float4(0.f, 0.f, 0.f, 0.f);
        if (n0 + lrow < N)
            bv = *(const float4*)(Bw + (size_t)(n0 + lrow) * ldb + k0 + lq);
        Bs[lq + 0][lrow] = bv.x; Bs[lq + 1][lrow] = bv.y;
        Bs[lq + 2][lrow] = bv.z; Bs[lq + 3][lrow] = bv.w;
        __syncthreads();
        #pragma unroll
        for (int kk = 0; kk < 16; ++kk) {
            float a_[4], b_[4];
            #pragma unroll
            for (int i = 0; i < 4; ++i) a_[i] = As[kk][ty * 4 + i];
            #pragma unroll
            for (int j = 0; j < 4; ++j) b_[j] = Bs[kk][tx * 4 + j];
            #pragma unroll
            for (int i = 0; i < 4; ++i)
                #pragma unroll
                for (int j = 0; j < 4; ++j)
                    acc[i][j] = fmaf(a_[i], b_[j], acc[i][j]);
        }
        __syncthreads();
    }
    #pragma unroll
    for (int i = 0; i < 4; ++i) {
        int m = m0 + ty * 4 + i;
        if (m >= M) continue;
        #pragma unroll
        for (int j = 0; j < 4; ++j) {
            int n = n0 + tx * 4 + j;
            if (n >= N) continue;
            float v = acc[i][j];
            if (FUSE == 1) { v += bias[n]; v = (v > 20.f) ? v : log1pf(__expf(v)); }
            if (FUSE == 2) { v = tanhf(v + bias[n]); }
            C[(size_t)m * ldc + n] = v;
        }
    }
}

// depthwise causal conv (width 4) + bias + SiLU over xi = xz[:, :DI]
__global__ __launch_bounds__(BDIM)
void conv_silu_k(const float* __restrict__ xz, const float* __restrict__ cw,
                 const float* __restrict__ cb, float* __restrict__ xc)
{
    int idx = blockIdx.x * BDIM + threadIdx.x;
    if (idx >= M1 * DI) return;
    int d = idx & (DI - 1);
    int m = idx >> 11;           // / DI
    int b = m / L_, l = m - b * L_;
    float acc = cb[d];
    #pragma unroll
    for (int t = 0; t < 4; ++t) {
        int ls = l - 3 + t;
        if (ls >= 0)
            acc = fmaf(cw[d * 4 + t], xz[(size_t)(b * L_ + ls) * DXZ + d], acc);
    }
    xc[idx] = acc * sigmoidf_(acc);
}

// selective scan: 16 lanes per (b,d) chain, one lane per state n.
// y (written in place over delta) = (sum_n h*C) + xc*D, then *= silu(z)
__global__ __launch_bounds__(BDIM)
void scan_k(const float* __restrict__ xz,    // z = xz[:, DI:]
            const float* __restrict__ xc,
            const float* __restrict__ xdbl,  // [:,64:80]=B, [:,80:96]=C
            const float* __restrict__ delta,
            const float* __restrict__ A_log,
            const float* __restrict__ Dp,
            float* __restrict__ y)
{
    const int grp = (blockIdx.x * BDIM + threadIdx.x) >> 4;
    const int n = threadIdx.x & 15;
    if (grp >= B_ * DI) return;
    const int b = grp >> 11;       // / DI
    const int d = grp & (DI - 1);
    const float Aa = -__expf(A_log[d * NST + n]);
    const float Dd = Dp[d];
    float h = 0.f;
    const float* dlt = delta + (size_t)b * L_ * DI + d;
    const float* xcd = xc + (size_t)b * L_ * DI + d;
    const float* zp  = xz + (size_t)b * L_ * DXZ + DI + d;
    const float* bc  = xdbl + (size_t)b * L_ * NXP + RNK;
    float* yp = y + (size_t)b * L_ * DI + d;
    for (int l = 0; l < L_; ++l) {
        float dv = dlt[(size_t)l * DI];
        float xv = xcd[(size_t)l * DI];
        float Bv = bc[(size_t)l * NXP + n];
        float Cv = bc[(size_t)l * NXP + NST + n];
        float dA = __expf(dv * Aa);
        h = fmaf(dA, h, dv * Bv * xv);
        float p = h * Cv;
        #pragma unroll
        for (int o = 8; o >= 1; o >>= 1) p += __shfl_xor(p, o, 16);
        if (n == 0) {
            float zv = zp[(size_t)l * DXZ];
            float yv = fmaf(xv, Dd, p);
            yv *= zv * sigmoidf_(zv);
            yp[(size_t)l * DI] = yv;
        }
    }
}

extern "C" void kernel_launch(void* const* d_in, const int* in_sizes, int n_in,
                              void* d_out, int out_size, void* d_ws, size_t ws_size,
                              hipStream_t stream) {
    const float* x         = (const float*)d_in[0];
    const float* in_proj_w = (const float*)d_in[1];
    const float* conv_w    = (const float*)d_in[2];
    const float* conv_b    = (const float*)d_in[3];
    const float* x_proj_w  = (const float*)d_in[4];
    const float* dt_proj_w = (const float*)d_in[5];
    const float* dt_proj_b = (const float*)d_in[6];
    const float* A_log     = (const float*)d_in[7];
    const float* Dp        = (const float*)d_in[8];
    const float* out_proj_w= (const float*)d_in[9];
    const float* fc1_w     = (const float*)d_in[10];
    const float* fc1_b     = (const float*)d_in[11];
    float* out = (float*)d_out;

    float* ws   = (float*)d_ws;
    float* xz   = ws;                               // M1*DXZ
    float* xc   = xz + (size_t)M1 * DXZ;            // M1*DI
    float* xdbl = xc + (size_t)M1 * DI;             // M1*NXP
    float* delta= xdbl + (size_t)M1 * NXP;          // M1*DI
    float* y    = delta;                            // alias: scan writes in place
    float* ym   = xz;                               // alias: xz dead after scan

    dim3 blk(BDIM);
    // 1) xz = x @ in_proj_w^T   (2000,1024)x(4096,1024)^T
    gemm_nt<0><<<dim3(DXZ / 64, (M1 + 63) / 64), blk, 0, stream>>>(
        x, DM, in_proj_w, DM, xz, DXZ, M1, DXZ, DM, nullptr);
    // 2) xc = silu(causal_conv4(xz[:, :DI]) + conv_b)
    conv_silu_k<<<(M1 * DI + BDIM - 1) / BDIM, blk, 0, stream>>>(xz, conv_w, conv_b, xc);
    // 3) xdbl = xc @ x_proj_w^T  (2000,2048)x(96,2048)^T
    gemm_nt<0><<<dim3((NXP + 63) / 64, (M1 + 63) / 64), blk, 0, stream>>>(
        xc, DI, x_proj_w, DI, xdbl, NXP, M1, NXP, DI, nullptr);
    // 4) delta = softplus(xdbl[:, :64] @ dt_proj_w^T + dt_proj_b)
    gemm_nt<1><<<dim3(DI / 64, (M1 + 63) / 64), blk, 0, stream>>>(
        xdbl, NXP, dt_proj_w, RNK, delta, DI, M1, DI, RNK, dt_proj_b);
    // 5) selective scan + D skip + silu(z) gate (y overwrites delta)
    scan_k<<<(B_ * DI * 16) / BDIM, blk, 0, stream>>>(xz, xc, xdbl, delta, A_log, Dp, y);
    // 6) ym = y @ out_proj_w^T   (2000,2048)x(1024,2048)^T  (ym overwrites xz)
    gemm_nt<0><<<dim3(DM / 64, (M1 + 63) / 64), blk, 0, stream>>>(
        y, DI, out_proj_w, DI, ym, DM, M1, DM, DI, nullptr);
    // 7) out = tanh(ym.view(200,10240) @ fc1_w^T + fc1_b)
    gemm_nt<2><<<dim3(DM / 64, (M2 + 63) / 64), blk, 0, stream>>>(
        ym, K2, fc1_w, K2, out, DM, M2, DM, K2, fc1_b);
    (void)in_sizes; (void)n_in; (void)out_size; (void)ws_size;
}

// Round 3
// 767.777 us; speedup vs baseline: 1.9513x; 1.9513x over previous
//
#include <hip/hip_runtime.h>
#include <math.h>

#define BDIM 256

constexpr int B_  = 4;
constexpr int L_  = 500;
constexpr int DM  = 1024;   // d_model
constexpr int DI  = 2048;   // d_inner
constexpr int DXZ = 4096;   // 2*d_inner
constexpr int RNK = 64;     // dt_rank
constexpr int NST = 16;     // d_state
constexpr int NXP = 96;     // dt_rank + 2*d_state
constexpr int M1  = B_ * L_;   // 2000 mamba tokens
constexpr int M2  = 200;       // fc1 rows (4*50)
constexpr int K2  = 10240;     // fc1 K

typedef __attribute__((ext_vector_type(8))) __bf16 bf16x8;
typedef __attribute__((ext_vector_type(4))) __bf16 bf16x4;
typedef __attribute__((ext_vector_type(4))) float  f32x4;

__device__ __forceinline__ float sigmoidf_(float x) { return 1.0f / (1.0f + __expf(-x)); }

// ---- staging: load fp32 tile [TR][32], split into bf16 hi/lo, write LDS ----
template<int TR>
__device__ __forceinline__ void stage_tile(const float* __restrict__ G, int ldg, int valid,
                                           __bf16 (*H)[40], __bf16 (*Lo)[40], int tid)
{
    #pragma unroll
    for (int i = 0; i < TR / 32; ++i) {
        int f = tid + i * 256;
        int r = f >> 3;
        int c = (f & 7) << 2;
        float4 v = make_float4(0.f, 0.f, 0.f, 0.f);
        if (r < valid) v = *(const float4*)(G + (size_t)r * ldg + c);
        float vv[4] = {v.x, v.y, v.z, v.w};
        bf16x4 hv, lv;
        #pragma unroll
        for (int j = 0; j < 4; ++j) {
            __bf16 h = (__bf16)vv[j];
            hv[j] = h;
            lv[j] = (__bf16)(vv[j] - (float)h);
        }
        *(bf16x4*)&H[r][c]  = hv;
        *(bf16x4*)&Lo[r][c] = lv;
    }
}

// C = A[M,K] * B[N,K]^T via bf16x3 split-precision MFMA (fp32-equivalent).
// 4 waves as 2x2; wave tile (FM*16)x(FN*16). BM=2*FM*16, BN=2*FN*16.
// blockIdx.z = K-split index (Kchunk per split); partials at C + z*csplit_stride.
// FUSE: 0 none, 1 softplus(x+bias[n])
template<int BM, int BN, int FM, int FN, int FUSE>
__global__ __launch_bounds__(256)
void gemm_mfma(const float* __restrict__ A, int lda,
               const float* __restrict__ Bw, int ldb,
               float* __restrict__ C, int ldc,
               int M, int N, int Kchunk, long csplit_stride,
               const float* __restrict__ bias)
{
    __shared__ __bf16 Ah[BM][40], Al[BM][40], Bh[BN][40], Bl[BN][40];
    const int tid  = threadIdx.x;
    const int lane = tid & 63;
    const int wave = tid >> 6;
    const int wm = wave >> 1, wn = wave & 1;
    const int m0 = blockIdx.y * BM;
    const int n0 = blockIdx.x * BN;
    const long kbase = (long)blockIdx.z * Kchunk;
    const float* Ap = A + (size_t)m0 * lda + kbase;
    const float* Bp = Bw + (size_t)n0 * ldb + kbase;
    const int validA = min(BM, M - m0);
    const int validB = min(BN, N - n0);
    f32x4 acc[FM][FN] = {};
    const int fr = lane & 15;
    const int kq = (lane >> 4) * 8;

    for (int k0 = 0; k0 < Kchunk; k0 += 32) {
        stage_tile<BM>(Ap + k0, lda, validA, Ah, Al, tid);
        stage_tile<BN>(Bp + k0, ldb, validB, Bh, Bl, tid);
        __syncthreads();
        bf16x8 ah[FM], al[FM], bh[FN], bl[FN];
        #pragma unroll
        for (int i = 0; i < FM; ++i) {
            int r = wm * (FM * 16) + i * 16 + fr;
            ah[i] = *(const bf16x8*)&Ah[r][kq];
            al[i] = *(const bf16x8*)&Al[r][kq];
        }
        #pragma unroll
        for (int j = 0; j < FN; ++j) {
            int r = wn * (FN * 16) + j * 16 + fr;
            bh[j] = *(const bf16x8*)&Bh[r][kq];
            bl[j] = *(const bf16x8*)&Bl[r][kq];
        }
        #pragma unroll
        for (int i = 0; i < FM; ++i)
            #pragma unroll
            for (int j = 0; j < FN; ++j) {
                acc[i][j] = __builtin_amdgcn_mfma_f32_16x16x32_bf16(ah[i], bh[j], acc[i][j], 0, 0, 0);
                acc[i][j] = __builtin_amdgcn_mfma_f32_16x16x32_bf16(ah[i], bl[j], acc[i][j], 0, 0, 0);
                acc[i][j] = __builtin_amdgcn_mfma_f32_16x16x32_bf16(al[i], bh[j], acc[i][j], 0, 0, 0);
            }
        __syncthreads();
    }

    float* Cp = C + (size_t)blockIdx.z * csplit_stride;
    #pragma unroll
    for (int i = 0; i < FM; ++i)
        #pragma unroll
        for (int j = 0; j < FN; ++j)
            #pragma unroll
            for (int r = 0; r < 4; ++r) {
                int gm = m0 + wm * (FM * 16) + i * 16 + (lane >> 4) * 4 + r;
                int gn = n0 + wn * (FN * 16) + j * 16 + (lane & 15);
                if (gm < M && gn < N) {
                    float v = acc[i][j][r];
                    if (FUSE == 1) { v += bias[gn]; v = (v > 20.f) ? v : log1pf(__expf(v)); }
                    Cp[(size_t)gm * ldc + gn] = v;
                }
            }
}

// sum split-K partials; FUSE: 0 none, 2 tanh(x + bias[n])
template<int FUSE>
__global__ __launch_bounds__(256)
void reduce_k(const float* __restrict__ part, float* __restrict__ C,
              int MN, int N, int S, long stride, const float* __restrict__ bias)
{
    int i = blockIdx.x * 256 + threadIdx.x;
    if (i >= MN) return;
    float s = 0.f;
    for (int j = 0; j < S; ++j) s += part[(size_t)j * stride + i];
    if (FUSE == 2) s = tanhf(s + bias[i % N]);
    C[i] = s;
}

// depthwise causal conv (width 4) + bias + SiLU over xi = xz[:, :DI]
__global__ __launch_bounds__(BDIM)
void conv_silu_k(const float* __restrict__ xz, const float* __restrict__ cw,
                 const float* __restrict__ cb, float* __restrict__ xc)
{
    int idx = blockIdx.x * BDIM + threadIdx.x;
    if (idx >= M1 * DI) return;
    int d = idx & (DI - 1);
    int m = idx >> 11;
    int b = m / L_, l = m - b * L_;
    float acc = cb[d];
    #pragma unroll
    for (int t = 0; t < 4; ++t) {
        int ls = l - 3 + t;
        if (ls >= 0)
            acc = fmaf(cw[d * 4 + t], xz[(size_t)(b * L_ + ls) * DXZ + d], acc);
    }
    xc[idx] = acc * sigmoidf_(acc);
}

// selective scan: 16 lanes per (b,d) chain, one lane per state n.
__global__ __launch_bounds__(BDIM)
void scan_k(const float* __restrict__ xz,    // z = xz[:, DI:]
            const float* __restrict__ xc,
            const float* __restrict__ xdbl,  // [:,64:80]=B, [:,80:96]=C
            const float* __restrict__ delta,
            const float* __restrict__ A_log,
            const float* __restrict__ Dp,
            float* __restrict__ y)
{
    const int grp = (blockIdx.x * BDIM + threadIdx.x) >> 4;
    const int n = threadIdx.x & 15;
    if (grp >= B_ * DI) return;
    const int b = grp >> 11;
    const int d = grp & (DI - 1);
    const float Aa = -__expf(A_log[d * NST + n]);
    const float Dd = Dp[d];
    float h = 0.f;
    const float* dlt = delta + (size_t)b * L_ * DI + d;
    const float* xcd = xc + (size_t)b * L_ * DI + d;
    const float* zp  = xz + (size_t)b * L_ * DXZ + DI + d;
    const float* bc  = xdbl + (size_t)b * L_ * NXP + RNK;
    float* yp = y + (size_t)b * L_ * DI + d;
    for (int l = 0; l < L_; ++l) {
        float dv = dlt[(size_t)l * DI];
        float xv = xcd[(size_t)l * DI];
        float Bv = bc[(size_t)l * NXP + n];
        float Cv = bc[(size_t)l * NXP + NST + n];
        float dA = __expf(dv * Aa);
        h = fmaf(dA, h, dv * Bv * xv);
        float p = h * Cv;
        #pragma unroll
        for (int o = 8; o >= 1; o >>= 1) p += __shfl_xor(p, o, 16);
        if (n == 0) {
            float zv = zp[(size_t)l * DXZ];
            float yv = fmaf(xv, Dd, p);
            yv *= zv * sigmoidf_(zv);
            yp[(size_t)l * DI] = yv;
        }
    }
}

extern "C" void kernel_launch(void* const* d_in, const int* in_sizes, int n_in,
                              void* d_out, int out_size, void* d_ws, size_t ws_size,
                              hipStream_t stream) {
    const float* x         = (const float*)d_in[0];
    const float* in_proj_w = (const float*)d_in[1];
    const float* conv_w    = (const float*)d_in[2];
    const float* conv_b    = (const float*)d_in[3];
    const float* x_proj_w  = (const float*)d_in[4];
    const float* dt_proj_w = (const float*)d_in[5];
    const float* dt_proj_b = (const float*)d_in[6];
    const float* A_log     = (const float*)d_in[7];
    const float* Dp        = (const float*)d_in[8];
    const float* out_proj_w= (const float*)d_in[9];
    const float* fc1_w     = (const float*)d_in[10];
    const float* fc1_b     = (const float*)d_in[11];
    float* out = (float*)d_out;

    float* ws    = (float*)d_ws;
    float* xz    = ws;                               // M1*DXZ (8.19M)
    float* xc    = xz + (size_t)M1 * DXZ;            // M1*DI  (4.10M)
    float* xdbl  = xc + (size_t)M1 * DI;             // M1*NXP (0.19M)
    float* delta = xdbl + (size_t)M1 * NXP;          // M1*DI  (4.10M)
    float* y     = delta;                            // alias: scan writes in place
    float* ym    = xz;                               // alias: xz dead after scan
    float* partx = delta;                            // alias: consumed before delta written
    float* partf = xc;                               // alias: xc dead after scan

    dim3 blk(BDIM);
    // 1) xz = x @ in_proj_w^T   (2000,1024)x(4096,1024)^T
    gemm_mfma<128,128,4,4,0><<<dim3(DXZ/128, (M1+127)/128, 1), blk, 0, stream>>>(
        x, DM, in_proj_w, DM, xz, DXZ, M1, DXZ, DM, 0, nullptr);
    // 2) xc = silu(causal_conv4(xz[:, :DI]) + conv_b)
    conv_silu_k<<<(M1*DI + BDIM-1)/BDIM, blk, 0, stream>>>(xz, conv_w, conv_b, xc);
    // 3) x_proj split-K=4: partx[s] = xc @ x_proj_w^T  (K chunks of 512)
    gemm_mfma<64,64,2,2,0><<<dim3((NXP+63)/64, (M1+63)/64, 4), blk, 0, stream>>>(
        xc, DI, x_proj_w, DI, partx, NXP, M1, NXP, DI/4, (long)M1*NXP, nullptr);
    // 4) xdbl = sum_s partx[s]
    reduce_k<0><<<(M1*NXP + 255)/256, blk, 0, stream>>>(
        partx, xdbl, M1*NXP, NXP, 4, (long)M1*NXP, nullptr);
    // 5) delta = softplus(xdbl[:, :64] @ dt_proj_w^T + dt_proj_b)
    gemm_mfma<64,64,2,2,1><<<dim3(DI/64, (M1+63)/64, 1), blk, 0, stream>>>(
        xdbl, NXP, dt_proj_w, RNK, delta, DI, M1, DI, RNK, 0, dt_proj_b);
    // 6) selective scan + D skip + silu(z) gate (y overwrites delta)
    scan_k<<<(B_*DI*16)/BDIM, blk, 0, stream>>>(xz, xc, xdbl, delta, A_log, Dp, y);
    // 7) ym = y @ out_proj_w^T   (2000,2048)x(1024,2048)^T  (ym overwrites xz)
    gemm_mfma<128,64,4,2,0><<<dim3(DM/64, (M1+127)/128, 1), blk, 0, stream>>>(
        y, DI, out_proj_w, DI, ym, DM, M1, DM, DI, 0, nullptr);
    // 8) fc1 split-K=20: partf[s] = ym.view(200,10240) @ fc1_w^T (K chunks of 512)
    gemm_mfma<64,64,2,2,0><<<dim3(DM/64, (M2+63)/64, 20), blk, 0, stream>>>(
        ym, K2, fc1_w, K2, partf, DM, M2, DM, K2/20, (long)M2*DM, nullptr);
    // 9) out = tanh(sum_s partf[s] + fc1_b)
    reduce_k<2><<<(M2*DM + 255)/256, blk, 0, stream>>>(
        partf, out, M2*DM, DM, 20, (long)M2*DM, fc1_b);
    (void)in_sizes; (void)n_in; (void)out_size; (void)ws_size;
}

// Round 5
// 535.080 us; speedup vs baseline: 2.7998x; 1.4349x over previous
//
#include <hip/hip_runtime.h>
#include <math.h>

#define BDIM 256

constexpr int B_  = 4;
constexpr int L_  = 500;
constexpr int DM  = 1024;   // d_model
constexpr int DI  = 2048;   // d_inner
constexpr int DXZ = 4096;   // 2*d_inner
constexpr int RNK = 64;     // dt_rank
constexpr int NST = 16;     // d_state
constexpr int NXP = 96;     // dt_rank + 2*d_state
constexpr int M1  = B_ * L_;   // 2000 mamba tokens
constexpr int M2  = 200;       // fc1 rows (4*50)
constexpr int K2  = 10240;     // fc1 K
constexpr int NC  = 10;        // scan chunks
constexpr int LC  = L_ / NC;   // 50 steps per chunk

typedef __attribute__((ext_vector_type(8))) __bf16 bf16x8;
typedef __attribute__((ext_vector_type(4))) __bf16 bf16x4;
typedef __attribute__((ext_vector_type(4))) float  f32x4;

__device__ __forceinline__ float sigmoidf_(float x) { return 1.0f / (1.0f + __expf(-x)); }

// ---- staging: load fp32 tile [TR][32], split into bf16 hi/lo, write LDS ----
template<int TR>
__device__ __forceinline__ void stage_tile(const float* __restrict__ G, int ldg, int valid,
                                           __bf16 (*H)[40], __bf16 (*Lo)[40], int tid)
{
    #pragma unroll
    for (int i = 0; i < TR / 32; ++i) {
        int f = tid + i * 256;
        int r = f >> 3;
        int c = (f & 7) << 2;
        float4 v = make_float4(0.f, 0.f, 0.f, 0.f);
        if (r < valid) v = *(const float4*)(G + (size_t)r * ldg + c);
        float vv[4] = {v.x, v.y, v.z, v.w};
        bf16x4 hv, lv;
        #pragma unroll
        for (int j = 0; j < 4; ++j) {
            __bf16 h = (__bf16)vv[j];
            hv[j] = h;
            lv[j] = (__bf16)(vv[j] - (float)h);
        }
        *(bf16x4*)&H[r][c]  = hv;
        *(bf16x4*)&Lo[r][c] = lv;
    }
}

// C = A[M,K] * B[N,K]^T via bf16x3 split-precision MFMA (fp32-equivalent).
// FUSE: 0 none, 1 softplus(x+bias[n])
template<int BM, int BN, int FM, int FN, int FUSE>
__global__ __launch_bounds__(256)
void gemm_mfma(const float* __restrict__ A, int lda,
               const float* __restrict__ Bw, int ldb,
               float* __restrict__ C, int ldc,
               int M, int N, int Kchunk, long csplit_stride,
               const float* __restrict__ bias)
{
    __shared__ __bf16 Ah[BM][40], Al[BM][40], Bh[BN][40], Bl[BN][40];
    const int tid  = threadIdx.x;
    const int lane = tid & 63;
    const int wave = tid >> 6;
    const int wm = wave >> 1, wn = wave & 1;
    const int m0 = blockIdx.y * BM;
    const int n0 = blockIdx.x * BN;
    const long kbase = (long)blockIdx.z * Kchunk;
    const float* Ap = A + (size_t)m0 * lda + kbase;
    const float* Bp = Bw + (size_t)n0 * ldb + kbase;
    const int validA = min(BM, M - m0);
    const int validB = min(BN, N - n0);
    f32x4 acc[FM][FN] = {};
    const int fr = lane & 15;
    const int kq = (lane >> 4) * 8;

    for (int k0 = 0; k0 < Kchunk; k0 += 32) {
        stage_tile<BM>(Ap + k0, lda, validA, Ah, Al, tid);
        stage_tile<BN>(Bp + k0, ldb, validB, Bh, Bl, tid);
        __syncthreads();
        bf16x8 ah[FM], al[FM], bh[FN], bl[FN];
        #pragma unroll
        for (int i = 0; i < FM; ++i) {
            int r = wm * (FM * 16) + i * 16 + fr;
            ah[i] = *(const bf16x8*)&Ah[r][kq];
            al[i] = *(const bf16x8*)&Al[r][kq];
        }
        #pragma unroll
        for (int j = 0; j < FN; ++j) {
            int r = wn * (FN * 16) + j * 16 + fr;
            bh[j] = *(const bf16x8*)&Bh[r][kq];
            bl[j] = *(const bf16x8*)&Bl[r][kq];
        }
        #pragma unroll
        for (int i = 0; i < FM; ++i)
            #pragma unroll
            for (int j = 0; j < FN; ++j) {
                acc[i][j] = __builtin_amdgcn_mfma_f32_16x16x32_bf16(ah[i], bh[j], acc[i][j], 0, 0, 0);
                acc[i][j] = __builtin_amdgcn_mfma_f32_16x16x32_bf16(ah[i], bl[j], acc[i][j], 0, 0, 0);
                acc[i][j] = __builtin_amdgcn_mfma_f32_16x16x32_bf16(al[i], bh[j], acc[i][j], 0, 0, 0);
            }
        __syncthreads();
    }

    float* Cp = C + (size_t)blockIdx.z * csplit_stride;
    #pragma unroll
    for (int i = 0; i < FM; ++i)
        #pragma unroll
        for (int j = 0; j < FN; ++j)
            #pragma unroll
            for (int r = 0; r < 4; ++r) {
                int gm = m0 + wm * (FM * 16) + i * 16 + (lane >> 4) * 4 + r;
                int gn = n0 + wn * (FN * 16) + j * 16 + (lane & 15);
                if (gm < M && gn < N) {
                    float v = acc[i][j][r];
                    if (FUSE == 1) { v += bias[gn]; v = (v > 20.f) ? v : log1pf(__expf(v)); }
                    Cp[(size_t)gm * ldc + gn] = v;
                }
            }
}

// sum split-K partials; FUSE: 0 none, 2 tanh(x + bias[n])
template<int FUSE>
__global__ __launch_bounds__(256)
void reduce_k(const float* __restrict__ part, float* __restrict__ C,
              int MN, int N, int S, long stride, const float* __restrict__ bias)
{
    int i = blockIdx.x * 256 + threadIdx.x;
    if (i >= MN) return;
    float s = 0.f;
    for (int j = 0; j < S; ++j) s += part[(size_t)j * stride + i];
    if (FUSE == 2) s = tanhf(s + bias[i % N]);
    C[i] = s;
}

// depthwise causal conv (width 4) + bias + SiLU over xi = xz[:, :DI]
__global__ __launch_bounds__(BDIM)
void conv_silu_k(const float* __restrict__ xz, const float* __restrict__ cw,
                 const float* __restrict__ cb, float* __restrict__ xc)
{
    int idx = blockIdx.x * BDIM + threadIdx.x;
    if (idx >= M1 * DI) return;
    int d = idx & (DI - 1);
    int m = idx >> 11;
    int b = m / L_, l = m - b * L_;
    float acc = cb[d];
    #pragma unroll
    for (int t = 0; t < 4; ++t) {
        int ls = l - 3 + t;
        if (ls >= 0)
            acc = fmaf(cw[d * 4 + t], xz[(size_t)(b * L_ + ls) * DXZ + d], acc);
    }
    xc[idx] = acc * sigmoidf_(acc);
}

// ---- chunked selective scan ----
// group g = (b*NC + c)*DI + d (d fastest -> wave's 4 groups on adjacent d);
// 16 lanes per group, one per state n.

// Phase A: chunk-local scan from h=0; store chunk-final h and prod(dA).
__global__ __launch_bounds__(BDIM)
void scan_partial_k(const float* __restrict__ delta, const float* __restrict__ xc,
                    const float* __restrict__ xdbl, const float* __restrict__ A_log,
                    float* __restrict__ hpart, float* __restrict__ aprod)
{
    const int g = (blockIdx.x * BDIM + threadIdx.x) >> 4;
    const int n = threadIdx.x & 15;
    const int d = g & (DI - 1);
    const int bc = g >> 11;
    const int b = bc / NC, c = bc - b * NC;
    const int l0 = c * LC;
    const float Aa = -__expf(A_log[d * NST + n]);
    const float* dlt = delta + ((size_t)(b * L_ + l0)) * DI + d;
    const float* xcd = xc    + ((size_t)(b * L_ + l0)) * DI + d;
    const float* bp  = xdbl  + ((size_t)(b * L_ + l0)) * NXP + RNK + n;
    float h = 0.f, ap = 1.f;
    for (int l = 0; l < LC; ++l) {
        float dv = dlt[(size_t)l * DI];
        float xv = xcd[(size_t)l * DI];
        float Bv = bp[(size_t)l * NXP];
        float dA = __expf(dv * Aa);
        h = fmaf(dA, h, dv * Bv * xv);
        ap *= dA;
    }
    size_t o = (size_t)g * NST + n;
    hpart[o] = h;
    aprod[o] = ap;
}

// Phase B: sequential over chunks per (b,d,n); hpart becomes hpre in place.
__global__ __launch_bounds__(BDIM)
void scan_fix_k(float* __restrict__ hpart, const float* __restrict__ aprod)
{
    const int i = blockIdx.x * BDIM + threadIdx.x;   // (b*DI + d)*16 + n
    if (i >= B_ * DI * NST) return;
    const int nn = i & (NST - 1);
    const int d  = (i >> 4) & (DI - 1);
    const int b  = i >> 15;
    float h = 0.f;
    for (int c = 0; c < NC; ++c) {
        size_t o = ((size_t)((b * NC + c) * DI + d)) * NST + nn;
        float hp = hpart[o];
        float ap = aprod[o];
        hpart[o] = h;                // hpre
        h = fmaf(ap, h, hp);
    }
}

// Phase C: re-run chunk from corrected h0; contract with C, gate, write y.
__global__ __launch_bounds__(BDIM)
void scan_final_k(const float* __restrict__ xz, const float* __restrict__ xc,
                  const float* __restrict__ xdbl, const float* __restrict__ delta,
                  const float* __restrict__ A_log, const float* __restrict__ Dp,
                  const float* __restrict__ hpre, float* __restrict__ y)
{
    const int g = (blockIdx.x * BDIM + threadIdx.x) >> 4;
    const int n = threadIdx.x & 15;
    const int d = g & (DI - 1);
    const int bc = g >> 11;
    const int b = bc / NC, c = bc - b * NC;
    const int l0 = c * LC;
    const float Aa = -__expf(A_log[d * NST + n]);
    const float Dd = Dp[d];
    const float* dlt = delta + ((size_t)(b * L_ + l0)) * DI + d;
    const float* xcd = xc    + ((size_t)(b * L_ + l0)) * DI + d;
    const float* bp  = xdbl  + ((size_t)(b * L_ + l0)) * NXP + RNK;
    const float* zp  = xz    + ((size_t)(b * L_ + l0)) * DXZ + DI + d;
    float* yp = y + ((size_t)(b * L_ + l0)) * DI + d;
    float h = hpre[(size_t)g * NST + n];
    for (int l = 0; l < LC; ++l) {
        float dv = dlt[(size_t)l * DI];
        float xv = xcd[(size_t)l * DI];
        float Bv = bp[(size_t)l * NXP + n];
        float Cv = bp[(size_t)l * NXP + NST + n];
        float dA = __expf(dv * Aa);
        h = fmaf(dA, h, dv * Bv * xv);
        float p = h * Cv;
        #pragma unroll
        for (int o = 8; o >= 1; o >>= 1) p += __shfl_xor(p, o, 16);
        if (n == 0) {
            float zv = zp[(size_t)l * DXZ];
            float yv = fmaf(xv, Dd, p);
            yv *= zv * sigmoidf_(zv);
            yp[(size_t)l * DI] = yv;
        }
    }
}

extern "C" void kernel_launch(void* const* d_in, const int* in_sizes, int n_in,
                              void* d_out, int out_size, void* d_ws, size_t ws_size,
                              hipStream_t stream) {
    const float* x         = (const float*)d_in[0];
    const float* in_proj_w = (const float*)d_in[1];
    const float* conv_w    = (const float*)d_in[2];
    const float* conv_b    = (const float*)d_in[3];
    const float* x_proj_w  = (const float*)d_in[4];
    const float* dt_proj_w = (const float*)d_in[5];
    const float* dt_proj_b = (const float*)d_in[6];
    const float* A_log     = (const float*)d_in[7];
    const float* Dp        = (const float*)d_in[8];
    const float* out_proj_w= (const float*)d_in[9];
    const float* fc1_w     = (const float*)d_in[10];
    const float* fc1_b     = (const float*)d_in[11];
    float* out = (float*)d_out;

    float* ws    = (float*)d_ws;
    float* xz    = ws;                               // M1*DXZ (8.19M f)
    float* xc    = xz + (size_t)M1 * DXZ;            // M1*DI  (4.10M f)
    float* xdbl  = xc + (size_t)M1 * DI;             // M1*NXP (0.19M f)
    float* delta = xdbl + (size_t)M1 * NXP;          // M1*DI  (4.10M f)
    float* hpart = delta + (size_t)M1 * DI;          // B*NC*DI*16 (1.31M f)
    float* aprod = hpart + (size_t)B_ * NC * DI * NST; // 1.31M f
    float* y     = delta;                            // alias: scan writes in place
    float* ym    = xz;                               // alias: xz dead after scan
    float* partx = delta;                            // alias: consumed before delta
    float* partf = xc;                               // alias: xc dead after scan

    dim3 blk(BDIM);
    // 1) xz = x @ in_proj_w^T
    gemm_mfma<128,128,4,4,0><<<dim3(DXZ/128, (M1+127)/128, 1), blk, 0, stream>>>(
        x, DM, in_proj_w, DM, xz, DXZ, M1, DXZ, DM, 0, nullptr);
    // 2) xc = silu(causal_conv4(xz[:, :DI]) + conv_b)
    conv_silu_k<<<(M1*DI + BDIM-1)/BDIM, blk, 0, stream>>>(xz, conv_w, conv_b, xc);
    // 3) x_proj split-K=4
    gemm_mfma<64,64,2,2,0><<<dim3((NXP+63)/64, (M1+63)/64, 4), blk, 0, stream>>>(
        xc, DI, x_proj_w, DI, partx, NXP, M1, NXP, DI/4, (long)M1*NXP, nullptr);
    // 4) xdbl = sum partials
    reduce_k<0><<<(M1*NXP + 255)/256, blk, 0, stream>>>(
        partx, xdbl, M1*NXP, NXP, 4, (long)M1*NXP, nullptr);
    // 5) delta = softplus(xdbl[:, :64] @ dt_proj_w^T + dt_proj_b)
    gemm_mfma<64,64,2,2,1><<<dim3(DI/64, (M1+63)/64, 1), blk, 0, stream>>>(
        xdbl, NXP, dt_proj_w, RNK, delta, DI, M1, DI, RNK, 0, dt_proj_b);
    // 6) chunked selective scan
    scan_partial_k<<<(B_*NC*DI*NST)/BDIM, blk, 0, stream>>>(
        delta, xc, xdbl, A_log, hpart, aprod);
    scan_fix_k<<<(B_*DI*NST + BDIM-1)/BDIM, blk, 0, stream>>>(hpart, aprod);
    scan_final_k<<<(B_*NC*DI*NST)/BDIM, blk, 0, stream>>>(
        xz, xc, xdbl, delta, A_log, Dp, hpart, y);
    // 7) ym = y @ out_proj_w^T
    gemm_mfma<128,64,4,2,0><<<dim3(DM/64, (M1+127)/128, 1), blk, 0, stream>>>(
        y, DI, out_proj_w, DI, ym, DM, M1, DM, DI, 0, nullptr);
    // 8) fc1 split-K=20
    gemm_mfma<64,64,2,2,0><<<dim3(DM/64, (M2+63)/64, 20), blk, 0, stream>>>(
        ym, K2, fc1_w, K2, partf, DM, M2, DM, K2/20, (long)M2*DM, nullptr);
    // 9) out = tanh(sum partials + fc1_b)
    reduce_k<2><<<(M2*DM + 255)/256, blk, 0, stream>>>(
        partf, out, M2*DM, DM, 20, (long)M2*DM, fc1_b);
    (void)in_sizes; (void)n_in; (void)out_size; (void)ws_size;
}

// Round 6
// 376.159 us; speedup vs baseline: 3.9827x; 1.4225x over previous
//
#include <hip/hip_runtime.h>
#include <math.h>

#define BDIM 256

constexpr int B_  = 4;
constexpr int L_  = 500;
constexpr int DM  = 1024;   // d_model
constexpr int DI  = 2048;   // d_inner
constexpr int DXZ = 4096;   // 2*d_inner
constexpr int RNK = 64;     // dt_rank
constexpr int NST = 16;     // d_state
constexpr int NXP = 96;     // dt_rank + 2*d_state
constexpr int M1  = B_ * L_;   // 2000 mamba tokens
constexpr int M2  = 200;       // fc1 rows (4*50)
constexpr int K2  = 10240;     // fc1 K
constexpr int NC  = 10;        // scan chunks
constexpr int LC  = L_ / NC;   // 50 steps per chunk

typedef __attribute__((ext_vector_type(8))) __bf16 bf16x8;
typedef __attribute__((ext_vector_type(4))) __bf16 bf16x4;
typedef __attribute__((ext_vector_type(4))) float  f32x4;

__device__ __forceinline__ float sigmoidf_(float x) { return 1.0f / (1.0f + __expf(-x)); }

// ---- global -> registers (prefetch) ----
template<int TR>
__device__ __forceinline__ void load_tile(const float* __restrict__ G, int ldg, int valid,
                                          float4* rg, int tid)
{
    #pragma unroll
    for (int i = 0; i < TR / 32; ++i) {
        int f = tid + i * 256;
        int r = f >> 3;
        int c = (f & 7) << 2;
        float4 v = make_float4(0.f, 0.f, 0.f, 0.f);
        if (r < valid) v = *(const float4*)(G + (size_t)r * ldg + c);
        rg[i] = v;
    }
}

// ---- registers -> LDS with bf16 hi/lo split ----
template<int TR>
__device__ __forceinline__ void write_tile(const float4* rg, __bf16 (*H)[40], __bf16 (*Lo)[40], int tid)
{
    #pragma unroll
    for (int i = 0; i < TR / 32; ++i) {
        int f = tid + i * 256;
        int r = f >> 3;
        int c = (f & 7) << 2;
        float vv[4] = {rg[i].x, rg[i].y, rg[i].z, rg[i].w};
        bf16x4 hv, lv;
        #pragma unroll
        for (int j = 0; j < 4; ++j) {
            __bf16 h = (__bf16)vv[j];
            hv[j] = h;
            lv[j] = (__bf16)(vv[j] - (float)h);
        }
        *(bf16x4*)&H[r][c]  = hv;
        *(bf16x4*)&Lo[r][c] = lv;
    }
}

// C = A[M,K] * B[N,K]^T via bf16x3 split-precision MFMA (fp32-equivalent).
// Register-prefetch pipeline: global loads for tile k+1 issue before tile k's MFMAs.
// FUSE: 0 none, 1 softplus(x+bias[n])
template<int BM, int BN, int FM, int FN, int FUSE>
__global__ __launch_bounds__(256)
void gemm_mfma(const float* __restrict__ A, int lda,
               const float* __restrict__ Bw, int ldb,
               float* __restrict__ C, int ldc,
               int M, int N, int Kchunk, long csplit_stride,
               const float* __restrict__ bias)
{
    __shared__ __bf16 Ah[BM][40], Al[BM][40], Bh[BN][40], Bl[BN][40];
    const int tid  = threadIdx.x;
    const int lane = tid & 63;
    const int wave = tid >> 6;
    const int wm = wave >> 1, wn = wave & 1;
    const int m0 = blockIdx.y * BM;
    const int n0 = blockIdx.x * BN;
    const long kbase = (long)blockIdx.z * Kchunk;
    const float* Ap = A + (size_t)m0 * lda + kbase;
    const float* Bp = Bw + (size_t)n0 * ldb + kbase;
    const int validA = min(BM, M - m0);
    const int validB = min(BN, N - n0);
    f32x4 acc[FM][FN] = {};
    const int fr = lane & 15;
    const int kq = (lane >> 4) * 8;

    float4 ra[BM / 32], rb[BN / 32];
    load_tile<BM>(Ap, lda, validA, ra, tid);
    load_tile<BN>(Bp, ldb, validB, rb, tid);

    for (int k0 = 0; k0 < Kchunk; k0 += 32) {
        write_tile<BM>(ra, Ah, Al, tid);
        write_tile<BN>(rb, Bh, Bl, tid);
        __syncthreads();
        if (k0 + 32 < Kchunk) {                 // prefetch next tile into regs
            load_tile<BM>(Ap + k0 + 32, lda, validA, ra, tid);
            load_tile<BN>(Bp + k0 + 32, ldb, validB, rb, tid);
        }
        bf16x8 ah[FM], al[FM], bh[FN], bl[FN];
        #pragma unroll
        for (int i = 0; i < FM; ++i) {
            int r = wm * (FM * 16) + i * 16 + fr;
            ah[i] = *(const bf16x8*)&Ah[r][kq];
            al[i] = *(const bf16x8*)&Al[r][kq];
        }
        #pragma unroll
        for (int j = 0; j < FN; ++j) {
            int r = wn * (FN * 16) + j * 16 + fr;
            bh[j] = *(const bf16x8*)&Bh[r][kq];
            bl[j] = *(const bf16x8*)&Bl[r][kq];
        }
        #pragma unroll
        for (int i = 0; i < FM; ++i)
            #pragma unroll
            for (int j = 0; j < FN; ++j) {
                acc[i][j] = __builtin_amdgcn_mfma_f32_16x16x32_bf16(ah[i], bh[j], acc[i][j], 0, 0, 0);
                acc[i][j] = __builtin_amdgcn_mfma_f32_16x16x32_bf16(ah[i], bl[j], acc[i][j], 0, 0, 0);
                acc[i][j] = __builtin_amdgcn_mfma_f32_16x16x32_bf16(al[i], bh[j], acc[i][j], 0, 0, 0);
            }
        __syncthreads();
    }

    float* Cp = C + (size_t)blockIdx.z * csplit_stride;
    #pragma unroll
    for (int i = 0; i < FM; ++i)
        #pragma unroll
        for (int j = 0; j < FN; ++j)
            #pragma unroll
            for (int r = 0; r < 4; ++r) {
                int gm = m0 + wm * (FM * 16) + i * 16 + (lane >> 4) * 4 + r;
                int gn = n0 + wn * (FN * 16) + j * 16 + (lane & 15);
                if (gm < M && gn < N) {
                    float v = acc[i][j][r];
                    if (FUSE == 1) { v += bias[gn]; v = (v > 20.f) ? v : log1pf(__expf(v)); }
                    Cp[(size_t)gm * ldc + gn] = v;
                }
            }
}

// sum split-K partials; FUSE: 0 none, 2 tanh(x + bias[n])
template<int FUSE>
__global__ __launch_bounds__(256)
void reduce_k(const float* __restrict__ part, float* __restrict__ C,
              int MN, int N, int S, long stride, const float* __restrict__ bias)
{
    int i = blockIdx.x * 256 + threadIdx.x;
    if (i >= MN) return;
    float s = 0.f;
    for (int j = 0; j < S; ++j) s += part[(size_t)j * stride + i];
    if (FUSE == 2) s = tanhf(s + bias[i % N]);
    C[i] = s;
}

// depthwise causal conv (width 4) + bias + SiLU over xi = xz[:, :DI]
__global__ __launch_bounds__(BDIM)
void conv_silu_k(const float* __restrict__ xz, const float* __restrict__ cw,
                 const float* __restrict__ cb, float* __restrict__ xc)
{
    int idx = blockIdx.x * BDIM + threadIdx.x;
    if (idx >= M1 * DI) return;
    int d = idx & (DI - 1);
    int m = idx >> 11;
    int b = m / L_, l = m - b * L_;
    float acc = cb[d];
    #pragma unroll
    for (int t = 0; t < 4; ++t) {
        int ls = l - 3 + t;
        if (ls >= 0)
            acc = fmaf(cw[d * 4 + t], xz[(size_t)(b * L_ + ls) * DXZ + d], acc);
    }
    xc[idx] = acc * sigmoidf_(acc);
}

// ---- chunked selective scan (3-phase) ----
__global__ __launch_bounds__(BDIM)
void scan_partial_k(const float* __restrict__ delta, const float* __restrict__ xc,
                    const float* __restrict__ xdbl, const float* __restrict__ A_log,
                    float* __restrict__ hpart, float* __restrict__ aprod)
{
    const int g = (blockIdx.x * BDIM + threadIdx.x) >> 4;
    const int n = threadIdx.x & 15;
    const int d = g & (DI - 1);
    const int bc = g >> 11;
    const int b = bc / NC, c = bc - b * NC;
    const int l0 = c * LC;
    const float Aa = -__expf(A_log[d * NST + n]);
    const float* dlt = delta + ((size_t)(b * L_ + l0)) * DI + d;
    const float* xcd = xc    + ((size_t)(b * L_ + l0)) * DI + d;
    const float* bp  = xdbl  + ((size_t)(b * L_ + l0)) * NXP + RNK + n;
    float h = 0.f, ap = 1.f;
    for (int l = 0; l < LC; ++l) {
        float dv = dlt[(size_t)l * DI];
        float xv = xcd[(size_t)l * DI];
        float Bv = bp[(size_t)l * NXP];
        float dA = __expf(dv * Aa);
        h = fmaf(dA, h, dv * Bv * xv);
        ap *= dA;
    }
    size_t o = (size_t)g * NST + n;
    hpart[o] = h;
    aprod[o] = ap;
}

__global__ __launch_bounds__(BDIM)
void scan_fix_k(float* __restrict__ hpart, const float* __restrict__ aprod)
{
    const int i = blockIdx.x * BDIM + threadIdx.x;   // (b*DI + d)*16 + n
    if (i >= B_ * DI * NST) return;
    const int nn = i & (NST - 1);
    const int d  = (i >> 4) & (DI - 1);
    const int b  = i >> 15;
    float h = 0.f;
    for (int c = 0; c < NC; ++c) {
        size_t o = ((size_t)((b * NC + c) * DI + d)) * NST + nn;
        float hp = hpart[o];
        float ap = aprod[o];
        hpart[o] = h;                // hpre
        h = fmaf(ap, h, hp);
    }
}

__global__ __launch_bounds__(BDIM)
void scan_final_k(const float* __restrict__ xz, const float* __restrict__ xc,
                  const float* __restrict__ xdbl, const float* __restrict__ delta,
                  const float* __restrict__ A_log, const float* __restrict__ Dp,
                  const float* __restrict__ hpre, float* __restrict__ y)
{
    const int g = (blockIdx.x * BDIM + threadIdx.x) >> 4;
    const int n = threadIdx.x & 15;
    const int d = g & (DI - 1);
    const int bc = g >> 11;
    const int b = bc / NC, c = bc - b * NC;
    const int l0 = c * LC;
    const float Aa = -__expf(A_log[d * NST + n]);
    const float Dd = Dp[d];
    const float* dlt = delta + ((size_t)(b * L_ + l0)) * DI + d;
    const float* xcd = xc    + ((size_t)(b * L_ + l0)) * DI + d;
    const float* bp  = xdbl  + ((size_t)(b * L_ + l0)) * NXP + RNK;
    const float* zp  = xz    + ((size_t)(b * L_ + l0)) * DXZ + DI + d;
    float* yp = y + ((size_t)(b * L_ + l0)) * DI + d;
    float h = hpre[(size_t)g * NST + n];
    for (int l = 0; l < LC; ++l) {
        float dv = dlt[(size_t)l * DI];
        float xv = xcd[(size_t)l * DI];
        float Bv = bp[(size_t)l * NXP + n];
        float Cv = bp[(size_t)l * NXP + NST + n];
        float dA = __expf(dv * Aa);
        h = fmaf(dA, h, dv * Bv * xv);
        float p = h * Cv;
        #pragma unroll
        for (int o = 8; o >= 1; o >>= 1) p += __shfl_xor(p, o, 16);
        if (n == 0) {
            float zv = zp[(size_t)l * DXZ];
            float yv = fmaf(xv, Dd, p);
            yv *= zv * sigmoidf_(zv);
            yp[(size_t)l * DI] = yv;
        }
    }
}

extern "C" void kernel_launch(void* const* d_in, const int* in_sizes, int n_in,
                              void* d_out, int out_size, void* d_ws, size_t ws_size,
                              hipStream_t stream) {
    const float* x         = (const float*)d_in[0];
    const float* in_proj_w = (const float*)d_in[1];
    const float* conv_w    = (const float*)d_in[2];
    const float* conv_b    = (const float*)d_in[3];
    const float* x_proj_w  = (const float*)d_in[4];
    const float* dt_proj_w = (const float*)d_in[5];
    const float* dt_proj_b = (const float*)d_in[6];
    const float* A_log     = (const float*)d_in[7];
    const float* Dp        = (const float*)d_in[8];
    const float* out_proj_w= (const float*)d_in[9];
    const float* fc1_w     = (const float*)d_in[10];
    const float* fc1_b     = (const float*)d_in[11];
    float* out = (float*)d_out;

    float* ws    = (float*)d_ws;
    float* xz    = ws;                               // M1*DXZ (8.19M f)
    float* xc    = xz + (size_t)M1 * DXZ;            // M1*DI  (4.10M f)
    float* xdbl  = xc + (size_t)M1 * DI;             // M1*NXP (0.19M f)
    float* delta = xdbl + (size_t)M1 * NXP;          // M1*DI  (4.10M f)
    float* hpart = delta + (size_t)M1 * DI;          // 1.31M f
    float* aprod = hpart + (size_t)B_ * NC * DI * NST; // 1.31M f
    float* y     = delta;   // alias: scan writes in place
    float* partx = delta;   // alias: x_proj partials, consumed before delta written
    float* partO = xz;      // alias: out_proj partials (xz dead after scan) 4*2.048M = 8.19M f
    float* ym    = xc;      // alias: out_proj result (xc dead after scan)
    float* partf = delta;   // alias: fc1 partials (y dead after out_proj) 20*0.2048M = 4.10M f

    dim3 blk(BDIM);
    // 1) xz = x @ in_proj_w^T  (64x128 tile, 1024 blocks)
    gemm_mfma<64,128,2,4,0><<<dim3(DXZ/128, (M1+63)/64, 1), blk, 0, stream>>>(
        x, DM, in_proj_w, DM, xz, DXZ, M1, DXZ, DM, 0, nullptr);
    // 2) xc = silu(causal_conv4(xz[:, :DI]) + conv_b)
    conv_silu_k<<<(M1*DI + BDIM-1)/BDIM, blk, 0, stream>>>(xz, conv_w, conv_b, xc);
    // 3) x_proj split-K=8 (512 blocks)
    gemm_mfma<64,64,2,2,0><<<dim3((NXP+63)/64, (M1+63)/64, 8), blk, 0, stream>>>(
        xc, DI, x_proj_w, DI, partx, NXP, M1, NXP, DI/8, (long)M1*NXP, nullptr);
    // 4) xdbl = sum partials
    reduce_k<0><<<(M1*NXP + 255)/256, blk, 0, stream>>>(
        partx, xdbl, M1*NXP, NXP, 8, (long)M1*NXP, nullptr);
    // 5) delta = softplus(xdbl[:, :64] @ dt_proj_w^T + dt_proj_b) (1024 blocks)
    gemm_mfma<64,64,2,2,1><<<dim3(DI/64, (M1+63)/64, 1), blk, 0, stream>>>(
        xdbl, NXP, dt_proj_w, RNK, delta, DI, M1, DI, RNK, 0, dt_proj_b);
    // 6) chunked selective scan
    scan_partial_k<<<(B_*NC*DI*NST)/BDIM, blk, 0, stream>>>(
        delta, xc, xdbl, A_log, hpart, aprod);
    scan_fix_k<<<(B_*DI*NST + BDIM-1)/BDIM, blk, 0, stream>>>(hpart, aprod);
    scan_final_k<<<(B_*NC*DI*NST)/BDIM, blk, 0, stream>>>(
        xz, xc, xdbl, delta, A_log, Dp, hpart, y);
    // 7) out_proj split-K=4 (2048 blocks): partO[s] = y @ out_proj_w^T chunks
    gemm_mfma<64,64,2,2,0><<<dim3(DM/64, (M1+63)/64, 4), blk, 0, stream>>>(
        y, DI, out_proj_w, DI, partO, DM, M1, DM, DI/4, (long)M1*DM, nullptr);
    // 8) ym = sum partials
    reduce_k<0><<<(M1*DM + 255)/256, blk, 0, stream>>>(
        partO, ym, M1*DM, DM, 4, (long)M1*DM, nullptr);
    // 9) fc1 split-K=20 (1280 blocks)
    gemm_mfma<64,64,2,2,0><<<dim3(DM/64, (M2+63)/64, 20), blk, 0, stream>>>(
        ym, K2, fc1_w, K2, partf, DM, M2, DM, K2/20, (long)M2*DM, nullptr);
    // 10) out = tanh(sum partials + fc1_b)
    reduce_k<2><<<(M2*DM + 255)/256, blk, 0, stream>>>(
        partf, out, M2*DM, DM, 20, (long)M2*DM, fc1_b);
    (void)in_sizes; (void)n_in; (void)out_size; (void)ws_size;
}

// Round 10
// 288.690 us; speedup vs baseline: 5.1895x; 1.3030x over previous
//
#include <hip/hip_runtime.h>
#include <math.h>

#define BDIM 256

constexpr int B_  = 4;
constexpr int L_  = 500;
constexpr int DM  = 1024;   // d_model
constexpr int DI  = 2048;   // d_inner
constexpr int DXZ = 4096;   // 2*d_inner
constexpr int RNK = 64;     // dt_rank
constexpr int NST = 16;     // d_state
constexpr int NXP = 96;     // dt_rank + 2*d_state
constexpr int M1  = B_ * L_;   // 2000 mamba tokens
constexpr int M2  = 200;       // fc1 rows (4*50)
constexpr int K2  = 10240;     // fc1 K
constexpr int NC  = 20;        // scan chunks
constexpr int LC  = L_ / NC;   // 25 steps per chunk

typedef __attribute__((ext_vector_type(8))) __bf16 bf16x8;
typedef __attribute__((ext_vector_type(4))) __bf16 bf16x4;
typedef __attribute__((ext_vector_type(4))) float  f32x4;

__device__ __forceinline__ float sigmoidf_(float x) { return 1.0f / (1.0f + __expf(-x)); }

// ---- global -> registers (prefetch) ----
template<int TR>
__device__ __forceinline__ void load_tile(const float* __restrict__ G, int ldg, int valid,
                                          float4* rg, int tid)
{
    #pragma unroll
    for (int i = 0; i < TR / 32; ++i) {
        int f = tid + i * 256;
        int r = f >> 3;
        int c = (f & 7) << 2;
        float4 v = make_float4(0.f, 0.f, 0.f, 0.f);
        if (r < valid) v = *(const float4*)(G + (size_t)r * ldg + c);
        rg[i] = v;
    }
}

// ---- registers -> LDS with bf16 hi/lo split ----
template<int TR>
__device__ __forceinline__ void write_tile(const float4* rg, __bf16 (*H)[40], __bf16 (*Lo)[40], int tid)
{
    #pragma unroll
    for (int i = 0; i < TR / 32; ++i) {
        int f = tid + i * 256;
        int r = f >> 3;
        int c = (f & 7) << 2;
        float vv[4] = {rg[i].x, rg[i].y, rg[i].z, rg[i].w};
        bf16x4 hv, lv;
        #pragma unroll
        for (int j = 0; j < 4; ++j) {
            __bf16 h = (__bf16)vv[j];
            hv[j] = h;
            lv[j] = (__bf16)(vv[j] - (float)h);
        }
        *(bf16x4*)&H[r][c]  = hv;
        *(bf16x4*)&Lo[r][c] = lv;
    }
}

// C = A[M,K] * B[N,K]^T via bf16x3 split-precision MFMA (fp32-equivalent).
// Register-prefetch pipeline. FUSE: 0 none, 1 softplus(x+bias[n])
template<int BM, int BN, int FM, int FN, int FUSE>
__global__ __launch_bounds__(256)
void gemm_mfma(const float* __restrict__ A, int lda,
               const float* __restrict__ Bw, int ldb,
               float* __restrict__ C, int ldc,
               int M, int N, int Kchunk, long csplit_stride,
               const float* __restrict__ bias)
{
    __shared__ __bf16 Ah[BM][40], Al[BM][40], Bh[BN][40], Bl[BN][40];
    const int tid  = threadIdx.x;
    const int lane = tid & 63;
    const int wave = tid >> 6;
    const int wm = wave >> 1, wn = wave & 1;
    const int m0 = blockIdx.y * BM;
    const int n0 = blockIdx.x * BN;
    const long kbase = (long)blockIdx.z * Kchunk;
    const float* Ap = A + (size_t)m0 * lda + kbase;
    const float* Bp = Bw + (size_t)n0 * ldb + kbase;
    const int validA = min(BM, M - m0);
    const int validB = min(BN, N - n0);
    f32x4 acc[FM][FN] = {};
    const int fr = lane & 15;
    const int kq = (lane >> 4) * 8;

    float4 ra[BM / 32], rb[BN / 32];
    load_tile<BM>(Ap, lda, validA, ra, tid);
    load_tile<BN>(Bp, ldb, validB, rb, tid);

    for (int k0 = 0; k0 < Kchunk; k0 += 32) {
        write_tile<BM>(ra, Ah, Al, tid);
        write_tile<BN>(rb, Bh, Bl, tid);
        __syncthreads();
        if (k0 + 32 < Kchunk) {                 // prefetch next tile into regs
            load_tile<BM>(Ap + k0 + 32, lda, validA, ra, tid);
            load_tile<BN>(Bp + k0 + 32, ldb, validB, rb, tid);
        }
        bf16x8 ah[FM], al[FM], bh[FN], bl[FN];
        #pragma unroll
        for (int i = 0; i < FM; ++i) {
            int r = wm * (FM * 16) + i * 16 + fr;
            ah[i] = *(const bf16x8*)&Ah[r][kq];
            al[i] = *(const bf16x8*)&Al[r][kq];
        }
        #pragma unroll
        for (int j = 0; j < FN; ++j) {
            int r = wn * (FN * 16) + j * 16 + fr;
            bh[j] = *(const bf16x8*)&Bh[r][kq];
            bl[j] = *(const bf16x8*)&Bl[r][kq];
        }
        #pragma unroll
        for (int i = 0; i < FM; ++i)
            #pragma unroll
            for (int j = 0; j < FN; ++j) {
                acc[i][j] = __builtin_amdgcn_mfma_f32_16x16x32_bf16(ah[i], bh[j], acc[i][j], 0, 0, 0);
                acc[i][j] = __builtin_amdgcn_mfma_f32_16x16x32_bf16(ah[i], bl[j], acc[i][j], 0, 0, 0);
                acc[i][j] = __builtin_amdgcn_mfma_f32_16x16x32_bf16(al[i], bh[j], acc[i][j], 0, 0, 0);
            }
        __syncthreads();
    }

    float* Cp = C + (size_t)blockIdx.z * csplit_stride;
    #pragma unroll
    for (int i = 0; i < FM; ++i)
        #pragma unroll
        for (int j = 0; j < FN; ++j)
            #pragma unroll
            for (int r = 0; r < 4; ++r) {
                int gm = m0 + wm * (FM * 16) + i * 16 + (lane >> 4) * 4 + r;
                int gn = n0 + wn * (FN * 16) + j * 16 + (lane & 15);
                if (gm < M && gn < N) {
                    float v = acc[i][j][r];
                    if (FUSE == 1) { v += bias[gn]; v = (v > 20.f) ? v : log1pf(__expf(v)); }
                    Cp[(size_t)gm * ldc + gn] = v;
                }
            }
}

// sum split-K partials; FUSE: 0 none, 2 tanh(x + bias[n])
template<int FUSE>
__global__ __launch_bounds__(256)
void reduce_k(const float* __restrict__ part, float* __restrict__ C,
              int MN, int N, int S, long stride, const float* __restrict__ bias)
{
    int i = blockIdx.x * 256 + threadIdx.x;
    if (i >= MN) return;
    float s = 0.f;
    for (int j = 0; j < S; ++j) s += part[(size_t)j * stride + i];
    if (FUSE == 2) s = tanhf(s + bias[i % N]);
    C[i] = s;
}

// depthwise causal conv (width 4) + bias + SiLU over xi = xz[:, :DI]
__global__ __launch_bounds__(BDIM)
void conv_silu_k(const float* __restrict__ xz, const float* __restrict__ cw,
                 const float* __restrict__ cb, float* __restrict__ xc)
{
    int idx = blockIdx.x * BDIM + threadIdx.x;
    if (idx >= M1 * DI) return;
    int d = idx & (DI - 1);
    int m = idx >> 11;
    int b = m / L_, l = m - b * L_;
    float acc = cb[d];
    #pragma unroll
    for (int t = 0; t < 4; ++t) {
        int ls = l - 3 + t;
        if (ls >= 0)
            acc = fmaf(cw[d * 4 + t], xz[(size_t)(b * L_ + ls) * DXZ + d], acc);
    }
    xc[idx] = acc * sigmoidf_(acc);
}

// ---- chunked selective scan: thread-per-chain, 16 states in registers ----
// t = (b*NC + c)*DI + d : d fastest -> dv/xv/zv/y coalesced; B/C wave-uniform.

__global__ __launch_bounds__(BDIM)
void scan_partial_k(const float* __restrict__ delta, const float* __restrict__ xc,
                    const float* __restrict__ xdbl, const float* __restrict__ A_log,
                    float* __restrict__ hpart, float* __restrict__ aprod)
{
    const int t = blockIdx.x * BDIM + threadIdx.x;
    const int d = t & (DI - 1);
    const int bc = t >> 11;
    const int b = bc / NC, c = bc - b * NC;
    const int l0 = c * LC;
    float Aa[NST];
    #pragma unroll
    for (int q = 0; q < 4; ++q) {
        float4 a4 = *(const float4*)(A_log + (size_t)d * NST + q * 4);
        Aa[q*4+0] = -__expf(a4.x); Aa[q*4+1] = -__expf(a4.y);
        Aa[q*4+2] = -__expf(a4.z); Aa[q*4+3] = -__expf(a4.w);
    }
    const float* dlt = delta + ((size_t)(b * L_ + l0)) * DI + d;
    const float* xcd = xc    + ((size_t)(b * L_ + l0)) * DI + d;
    const float* bp  = xdbl  + ((size_t)(b * L_ + l0)) * NXP + RNK;
    float h[NST] = {};
    float sdv = 0.f;
    for (int l = 0; l < LC; ++l) {
        float dv = dlt[(size_t)l * DI];
        float xv = xcd[(size_t)l * DI];
        const float4* b4 = (const float4*)(bp + (size_t)l * NXP);
        float dvx = dv * xv;
        sdv += dv;
        #pragma unroll
        for (int q = 0; q < 4; ++q) {
            float4 Bq = b4[q];
            float bb[4] = {Bq.x, Bq.y, Bq.z, Bq.w};
            #pragma unroll
            for (int j = 0; j < 4; ++j) {
                int n = q * 4 + j;
                float dA = __expf(dv * Aa[n]);
                h[n] = fmaf(dA, h[n], dvx * bb[j]);
            }
        }
    }
    // prod(dA) over chunk = exp(Aa * sum(dv))
    float4* hp4 = (float4*)(hpart + (size_t)t * NST);
    float4* ap4 = (float4*)(aprod + (size_t)t * NST);
    #pragma unroll
    for (int q = 0; q < 4; ++q) {
        hp4[q] = make_float4(h[q*4], h[q*4+1], h[q*4+2], h[q*4+3]);
        ap4[q] = make_float4(__expf(Aa[q*4+0]*sdv), __expf(Aa[q*4+1]*sdv),
                             __expf(Aa[q*4+2]*sdv), __expf(Aa[q*4+3]*sdv));
    }
}

__global__ __launch_bounds__(BDIM)
void scan_fix_k(float* __restrict__ hpart, const float* __restrict__ aprod)
{
    const int i = blockIdx.x * BDIM + threadIdx.x;   // (b*DI + d)*16 + n
    if (i >= B_ * DI * NST) return;
    const int nn = i & (NST - 1);
    const int d  = (i >> 4) & (DI - 1);
    const int b  = i >> 15;
    float h = 0.f;
    for (int c = 0; c < NC; ++c) {
        size_t o = ((size_t)((b * NC + c) * DI + d)) * NST + nn;
        float hp = hpart[o];
        float ap = aprod[o];
        hpart[o] = h;                // hpre
        h = fmaf(ap, h, hp);
    }
}

__global__ __launch_bounds__(BDIM)
void scan_final_k(const float* __restrict__ xz, const float* __restrict__ xc,
                  const float* __restrict__ xdbl, const float* __restrict__ delta,
                  const float* __restrict__ A_log, const float* __restrict__ Dp,
                  const float* __restrict__ hpre, float* __restrict__ y)
{
    const int t = blockIdx.x * BDIM + threadIdx.x;
    const int d = t & (DI - 1);
    const int bc = t >> 11;
    const int b = bc / NC, c = bc - b * NC;
    const int l0 = c * LC;
    float Aa[NST];
    #pragma unroll
    for (int q = 0; q < 4; ++q) {
        float4 a4 = *(const float4*)(A_log + (size_t)d * NST + q * 4);
        Aa[q*4+0] = -__expf(a4.x); Aa[q*4+1] = -__expf(a4.y);
        Aa[q*4+2] = -__expf(a4.z); Aa[q*4+3] = -__expf(a4.w);
    }
    float h[NST];
    const float4* h4 = (const float4*)(hpre + (size_t)t * NST);
    #pragma unroll
    for (int q = 0; q < 4; ++q) {
        float4 hv = h4[q];
        h[q*4+0] = hv.x; h[q*4+1] = hv.y; h[q*4+2] = hv.z; h[q*4+3] = hv.w;
    }
    const float Dd = Dp[d];
    const float* dlt = delta + ((size_t)(b * L_ + l0)) * DI + d;
    const float* xcd = xc    + ((size_t)(b * L_ + l0)) * DI + d;
    const float* bp  = xdbl  + ((size_t)(b * L_ + l0)) * NXP + RNK;
    const float* zp  = xz    + ((size_t)(b * L_ + l0)) * DXZ + DI + d;
    float* yp = y + ((size_t)(b * L_ + l0)) * DI + d;
    for (int l = 0; l < LC; ++l) {
        float dv = dlt[(size_t)l * DI];
        float xv = xcd[(size_t)l * DI];
        const float4* b4 = (const float4*)(bp + (size_t)l * NXP);
        float dvx = dv * xv;
        float p = 0.f;
        #pragma unroll
        for (int q = 0; q < 4; ++q) {
            float4 Bq = b4[q];
            float4 Cq = b4[4 + q];
            float bb[4] = {Bq.x, Bq.y, Bq.z, Bq.w};
            float cc[4] = {Cq.x, Cq.y, Cq.z, Cq.w};
            #pragma unroll
            for (int j = 0; j < 4; ++j) {
                int n = q * 4 + j;
                float dA = __expf(dv * Aa[n]);
                h[n] = fmaf(dA, h[n], dvx * bb[j]);
                p = fmaf(h[n], cc[j], p);
            }
        }
        float zv = zp[(size_t)l * DXZ];
        float yv = fmaf(xv, Dd, p);
        yv *= zv * sigmoidf_(zv);
        yp[(size_t)l * DI] = yv;
    }
}

extern "C" void kernel_launch(void* const* d_in, const int* in_sizes, int n_in,
                              void* d_out, int out_size, void* d_ws, size_t ws_size,
                              hipStream_t stream) {
    const float* x         = (const float*)d_in[0];
    const float* in_proj_w = (const float*)d_in[1];
    const float* conv_w    = (const float*)d_in[2];
    const float* conv_b    = (const float*)d_in[3];
    const float* x_proj_w  = (const float*)d_in[4];
    const float* dt_proj_w = (const float*)d_in[5];
    const float* dt_proj_b = (const float*)d_in[6];
    const float* A_log     = (const float*)d_in[7];
    const float* Dp        = (const float*)d_in[8];
    const float* out_proj_w= (const float*)d_in[9];
    const float* fc1_w     = (const float*)d_in[10];
    const float* fc1_b     = (const float*)d_in[11];
    float* out = (float*)d_out;

    float* ws    = (float*)d_ws;
    float* xz    = ws;                               // M1*DXZ (8.19M f)
    float* xc    = xz + (size_t)M1 * DXZ;            // M1*DI  (4.10M f)
    float* xdbl  = xc + (size_t)M1 * DI;             // M1*NXP (0.19M f)
    float* delta = xdbl + (size_t)M1 * NXP;          // M1*DI  (4.10M f)
    float* hpart = delta + (size_t)M1 * DI;          // B*NC*DI*16 (2.62M f)
    float* aprod = hpart + (size_t)B_ * NC * DI * NST; // 2.62M f
    float* y     = delta;   // alias: scan writes in place
    float* partx = delta;   // alias: x_proj partials, consumed before delta written
    float* partO = xz;      // alias: out_proj partials (xz dead after scan)
    float* ym    = xc;      // alias: out_proj result (xc dead after scan)
    float* partf = delta;   // alias: fc1 partials (y dead after out_proj)

    dim3 blk(BDIM);
    // 1) xz = x @ in_proj_w^T  (64x128 tile, 1024 blocks)
    gemm_mfma<64,128,2,4,0><<<dim3(DXZ/128, (M1+63)/64, 1), blk, 0, stream>>>(
        x, DM, in_proj_w, DM, xz, DXZ, M1, DXZ, DM, 0, nullptr);
    // 2) xc = silu(causal_conv4(xz[:, :DI]) + conv_b)
    conv_silu_k<<<(M1*DI + BDIM-1)/BDIM, blk, 0, stream>>>(xz, conv_w, conv_b, xc);
    // 3) x_proj split-K=8 (512 blocks)
    gemm_mfma<64,64,2,2,0><<<dim3((NXP+63)/64, (M1+63)/64, 8), blk, 0, stream>>>(
        xc, DI, x_proj_w, DI, partx, NXP, M1, NXP, DI/8, (long)M1*NXP, nullptr);
    // 4) xdbl = sum partials
    reduce_k<0><<<(M1*NXP + 255)/256, blk, 0, stream>>>(
        partx, xdbl, M1*NXP, NXP, 8, (long)M1*NXP, nullptr);
    // 5) delta = softplus(xdbl[:, :64] @ dt_proj_w^T + dt_proj_b) (1024 blocks)
    gemm_mfma<64,64,2,2,1><<<dim3(DI/64, (M1+63)/64, 1), blk, 0, stream>>>(
        xdbl, NXP, dt_proj_w, RNK, delta, DI, M1, DI, RNK, 0, dt_proj_b);
    // 6) chunked selective scan (thread-per-chain)
    scan_partial_k<<<(B_*NC*DI)/BDIM, blk, 0, stream>>>(
        delta, xc, xdbl, A_log, hpart, aprod);
    scan_fix_k<<<(B_*DI*NST + BDIM-1)/BDIM, blk, 0, stream>>>(hpart, aprod);
    scan_final_k<<<(B_*NC*DI)/BDIM, blk, 0, stream>>>(
        xz, xc, xdbl, delta, A_log, Dp, hpart, y);
    // 7) out_proj split-K=4 (2048 blocks)
    gemm_mfma<64,64,2,2,0><<<dim3(DM/64, (M1+63)/64, 4), blk, 0, stream>>>(
        y, DI, out_proj_w, DI, partO, DM, M1, DM, DI/4, (long)M1*DM, nullptr);
    // 8) ym = sum partials
    reduce_k<0><<<(M1*DM + 255)/256, blk, 0, stream>>>(
        partO, ym, M1*DM, DM, 4, (long)M1*DM, nullptr);
    // 9) fc1 split-K=20 (1280 blocks)
    gemm_mfma<64,64,2,2,0><<<dim3(DM/64, (M2+63)/64, 20), blk, 0, stream>>>(
        ym, K2, fc1_w, K2, partf, DM, M2, DM, K2/20, (long)M2*DM, nullptr);
    // 10) out = tanh(sum partials + fc1_b)
    reduce_k<2><<<(M2*DM + 255)/256, blk, 0, stream>>>(
        partf, out, M2*DM, DM, 20, (long)M2*DM, fc1_b);
    (void)in_sizes; (void)n_in; (void)out_size; (void)ws_size;
}